// Round 2
// baseline (147.529 us; speedup 1.0000x reference)
//
#include <hip/hip_runtime.h>
#include <math.h>

constexpr int BS = 32, NP = 64, NV = 321, PL = 12, DM = 128;
constexpr int KT = 32;  // int(64*0.5) patches masked by time criterion
constexpr int KF = 25;  // int(64*0.4) patches masked by freq criterion
constexpr int VB = 8;                       // variables per block
constexpr int NCHUNK = (NV + VB - 1) / VB;  // 41
// LDS row stride per vv: 64 patches * 13 floats (+4 so row stride % 32 == 4,
// spreading banks across vv for the staging scatter-writes)
constexpr int RSTRIDE = 64 * 13 + 4;  // 836 floats

// map float -> uint such that uint order == float order (total, -0 < +0)
__device__ __forceinline__ unsigned ord(float f) {
  unsigned u = __float_as_uint(f);
  return ((int)u < 0) ? ~u : (u | 0x80000000u);
}

// keep = NOT among the K largest of u across the 64-lane wave
// (ties: lower lane index is taken first, matching stable lax.top_k)
__device__ __forceinline__ bool keep_not_topk(unsigned u, int K, int lane) {
  unsigned thr = 0;
#pragma unroll
  for (int bit = 31; bit >= 0; --bit) {
    unsigned cand = thr | (1u << bit);
    unsigned long long b = __ballot(u >= cand);
    if (__popcll(b) >= K) thr = cand;  // thr ends as the K-th largest value
  }
  int cnt_gt = __popcll(__ballot(u > thr));
  unsigned long long eq = __ballot(u == thr);
  int r_eq = __popcll(eq & ((1ull << lane) - 1ull));
  bool masked = (u > thr) || ((u == thr) && (r_eq < (K - cnt_gt)));
  return !masked;
}

__global__ __launch_bounds__(256) void fused_kernel(
    const float* __restrict__ x, const float* __restrict__ W_in,
    const float* __restrict__ b_in, const float* __restrict__ W_out,
    const float* __restrict__ b_out, const float* __restrict__ tt,
    const float* __restrict__ ft, float* __restrict__ out) {
  __shared__ float xs[VB * RSTRIDE];  // 26.1 KB transposed x tile
  __shared__ float sM[144];           // M = W_in @ W_out, row-major [i][l]
  __shared__ float sc[12], sSt[12], sSf[12], sb[12];
  __shared__ unsigned long long smT[VB], smF[VB];

  const int t = threadIdx.x;
  const int blk = blockIdx.x;
  const int b = blk / NCHUNK;
  const int chunk = blk - b * NCHUNK;
  const int v0 = chunk * VB;
  const int nv = min(VB, NV - v0);  // 8, or 1 for the last chunk

  // ---- phase 0a: issue staged loads (coalesced float4, 384B runs per p) ----
  const float* xb = x + (size_t)(b * 64) * (NV * PL) + v0 * PL;
  const int nf4 = 64 * nv * 3;  // float4s in this tile
  float4 st[6];
  int soff[6];
  int cnt = 0;
  for (int j = t; j < nf4; j += 256) {
    int p = j / (nv * 3);
    int r = j - p * (nv * 3);
    int vv = r / 3;
    int l0 = (r - vv * 3) * 4;
    st[cnt] = *(const float4*)(xb + (size_t)p * (NV * PL) + vv * PL + l0);
    soff[cnt] = vv * RSTRIDE + p * 13 + l0;
    ++cnt;
  }

  // ---- phase 0b: per-block prep (overlaps staging load latency) ----
  // sM[i][l] = sum_d W_in[i][d]*W_out[d][l]; sc = b_in@W_out;
  // sSt/sSf = token * colsum(W_out); sb = b_out
  if (t < 144) {
    const int i = t / 12, l = t - (t / 12) * 12;
    const float4* Wi = (const float4*)(W_in + i * DM);
    float acc = 0.f;
#pragma unroll 8
    for (int d4 = 0; d4 < 32; ++d4) {
      float4 a = Wi[d4];
      const float* wo = W_out + d4 * 48 + l;
      acc += a.x * wo[0];
      acc += a.y * wo[12];
      acc += a.z * wo[24];
      acc += a.w * wo[36];
    }
    sM[t] = acc;
  } else if (t < 168) {
    const int l = (t - 144) % 12;
    float cs = 0.f, cb = 0.f;
#pragma unroll 8
    for (int d = 0; d < DM; ++d) {
      float w = W_out[d * 12 + l];
      cs += w;
      cb += b_in[d] * w;
    }
    if (t < 156) {
      sc[l] = cb;
      sSt[l] = tt[0] * cs;
    } else {
      sSf[l] = ft[0] * cs;
    }
  } else if (t < 180) {
    sb[t - 168] = b_out[t - 168];
  }

  // ---- phase 0c: scatter staged data into transposed LDS layout ----
  for (int q = 0; q < cnt; ++q) {
    float* d = xs + soff[q];
    d[0] = st[q].x;
    d[1] = st[q].y;
    d[2] = st[q].z;
    d[3] = st[q].w;
  }
  __syncthreads();

  // ---- phase 1: scores + in-wave radix top-k, one wave per vv, lane = p ----
  const int wv = t >> 6, lane = t & 63;
  const float H = 0.86602540378443864676f;  // sqrt(3)/2
#pragma unroll
  for (int k = 0; k < 2; ++k) {
    const int vv = wv * 2 + k;
    if (vv < nv) {  // wave-uniform branch: all 64 lanes together
      const float* xp = xs + vv * RSTRIDE + lane * 13;
      float xv[12];
#pragma unroll
      for (int i = 0; i < 12; ++i) xv[i] = xp[i];

      // coefficient of variation: std(ddof=1)/(mean+1e-6)
      float s = 0.f;
#pragma unroll
      for (int i = 0; i < 12; ++i) s += xv[i];
      const float m = s * (1.0f / 12.0f);
      float ss = 0.f;
#pragma unroll
      for (int i = 0; i < 12; ++i) {
        float d = xv[i] - m;
        ss += d * d;
      }
      const float cv = sqrtf(ss * (1.0f / 11.0f)) / (m + 1e-6f);

      // mean |rfft12| over 7 bins, even/odd folded exact 30-degree DFT
      const float e1 = xv[1] + xv[11], e2 = xv[2] + xv[10],
                  e3 = xv[3] + xv[9], e4 = xv[4] + xv[8], e5 = xv[5] + xv[7];
      const float o1 = xv[1] - xv[11], o2 = xv[2] - xv[10],
                  o3 = xv[3] - xv[9], o4 = xv[4] - xv[8], o5 = xv[5] - xv[7];
      float mag = fabsf(xv[0] + xv[6] + e1 + e2 + e3 + e4 + e5);  // k=0
      float re = xv[0] - xv[6] + H * (e1 - e5) + 0.5f * (e2 - e4);
      float im = 0.5f * (o1 + o5) + H * (o2 + o4) + o3;
      mag += sqrtf(re * re + im * im);  // k=1
      re = xv[0] + xv[6] + 0.5f * (e1 + e5) - 0.5f * (e2 + e4) - e3;
      im = H * (o1 + o2 - o4 - o5);
      mag += sqrtf(re * re + im * im);  // k=2
      re = xv[0] - xv[6] - e2 + e4;
      im = o1 - o3 + o5;
      mag += sqrtf(re * re + im * im);  // k=3
      re = xv[0] + xv[6] - 0.5f * (e1 + e2 + e4 + e5) + e3;
      im = H * (o1 - o2 + o4 - o5);
      mag += sqrtf(re * re + im * im);  // k=4
      re = xv[0] - xv[6] + H * (e5 - e1) + 0.5f * (e2 - e4);
      im = 0.5f * (o1 + o5) - H * (o2 + o4) + o3;
      mag += sqrtf(re * re + im * im);  // k=5
      re = xv[0] + xv[6] - e1 + e2 - e3 + e4 - e5;
      mag += fabsf(re);  // k=6
      const float fs = mag * (1.0f / 7.0f);

      const bool kt = keep_not_topk(ord(cv), KT, lane);   // mask KT largest cv
      const bool kf = keep_not_topk(~ord(fs), KF, lane);  // mask KF smallest fs
      unsigned long long bt = __ballot(kt), bf = __ballot(kf);
      if (lane == 0) {
        smT[vv] = bt;
        smF[vv] = bf;
      }
    }
  }
  __syncthreads();

  // ---- phase 2: decode. thread -> (p, vv0), (p, vv0+1); M rows broadcast ----
  const int p2 = t >> 2;
  const int vv0 = (t & 3) * 2;
  float xv2[2][12], E[2][12];
  const bool val0 = vv0 < nv, val1 = (vv0 + 1) < nv;
#pragma unroll
  for (int j = 0; j < 2; ++j) {
    const float* xp = xs + (vv0 + j) * RSTRIDE + p2 * 13;
#pragma unroll
    for (int i = 0; i < 12; ++i) xv2[j][i] = xp[i];  // in-bounds even if !valid
  }
#pragma unroll
  for (int l = 0; l < 12; ++l) {
    E[0][l] = sc[l];
    E[1][l] = sc[l];
  }
  const float4* M4 = (const float4*)sM;
#pragma unroll
  for (int i = 0; i < 12; ++i) {  // uniform-address b128 broadcasts
    float4 m0 = M4[i * 3], m1 = M4[i * 3 + 1], m2 = M4[i * 3 + 2];
    float a0 = xv2[0][i], a1 = xv2[1][i];
    E[0][0] += a0 * m0.x;  E[0][1] += a0 * m0.y;
    E[0][2] += a0 * m0.z;  E[0][3] += a0 * m0.w;
    E[0][4] += a0 * m1.x;  E[0][5] += a0 * m1.y;
    E[0][6] += a0 * m1.z;  E[0][7] += a0 * m1.w;
    E[0][8] += a0 * m2.x;  E[0][9] += a0 * m2.y;
    E[0][10] += a0 * m2.z; E[0][11] += a0 * m2.w;
    E[1][0] += a1 * m0.x;  E[1][1] += a1 * m0.y;
    E[1][2] += a1 * m0.z;  E[1][3] += a1 * m0.w;
    E[1][4] += a1 * m1.x;  E[1][5] += a1 * m1.y;
    E[1][6] += a1 * m1.z;  E[1][7] += a1 * m1.w;
    E[1][8] += a1 * m2.x;  E[1][9] += a1 * m2.y;
    E[1][10] += a1 * m2.z; E[1][11] += a1 * m2.w;
  }
#pragma unroll
  for (int j = 0; j < 2; ++j) {
    if (j == 0 ? val0 : val1) {
      const int vv = vv0 + j;
      const bool kt = (smT[vv] >> p2) & 1ull;
      const bool kf = (smF[vv] >> p2) & 1ull;
      float o[12];
#pragma unroll
      for (int l = 0; l < 12; ++l) {
        float e = E[j][l];
        float at = kt ? e : sSt[l];
        float af = kf ? e : sSf[l];
        o[l] = 0.5f * (at + af) + sb[l];
      }
      float* op = out + ((size_t)(b * 64 + p2) * NV + v0 + vv) * PL;
      ((float4*)op)[0] = make_float4(o[0], o[1], o[2], o[3]);
      ((float4*)op)[1] = make_float4(o[4], o[5], o[6], o[7]);
      ((float4*)op)[2] = make_float4(o[8], o[9], o[10], o[11]);
    }
  }
}

extern "C" void kernel_launch(void* const* d_in, const int* in_sizes, int n_in,
                              void* d_out, int out_size, void* d_ws,
                              size_t ws_size, hipStream_t stream) {
  const float* x = (const float*)d_in[0];
  const float* W_in = (const float*)d_in[1];
  const float* b_in = (const float*)d_in[2];
  const float* W_out = (const float*)d_in[3];
  const float* b_out = (const float*)d_in[4];
  const float* tt = (const float*)d_in[5];
  const float* ft = (const float*)d_in[6];
  float* out = (float*)d_out;

  hipLaunchKernelGGL(fused_kernel, dim3(BS * NCHUNK), dim3(256), 0, stream, x,
                     W_in, b_in, W_out, b_out, tt, ft, out);
}

// Round 3
// 119.989 us; speedup vs baseline: 1.2295x; 1.2295x over previous
//
#include <hip/hip_runtime.h>
#include <math.h>

constexpr int BS = 32, NP = 64, NV = 321, PL = 12, DM = 128;
constexpr int KT = 32;  // int(64*0.5) patches masked by time criterion
constexpr int KF = 25;  // int(64*0.4) patches masked by freq criterion
constexpr int VB = 8;         // variables per block
constexpr int NCHUNK = 41;    // 40 full chunks + 1 chunk with nv=1
constexpr int RSTRIDE = 64 * 13 + 4;  // 836 floats per vv row (13-stride: bank-friendly)

// map float -> uint such that uint order == float order (total, -0 < +0)
__device__ __forceinline__ unsigned ord(float f) {
  unsigned u = __float_as_uint(f);
  return ((int)u < 0) ? ~u : (u | 0x80000000u);
}

// ---------------------------------------------------------------------------
// prep: M = W_in @ W_out (12x12), c = b_in @ W_out (12),
//       S_t = tt * colsum(W_out), S_f = ft * colsum(W_out)
// ws floats: [0,144) M row-major [i][l], [144,156) c, [156,168) S_t, [168,180) S_f
// ---------------------------------------------------------------------------
__global__ void prep_kernel(const float* __restrict__ W_in,
                            const float* __restrict__ b_in,
                            const float* __restrict__ W_out,
                            const float* __restrict__ tt,
                            const float* __restrict__ ft,
                            float* __restrict__ prep) {
  int t = threadIdx.x;
  if (t < 144) {
    int i = t / 12, l = t % 12;
    const float4* Wi = (const float4*)(W_in + i * DM);
    float s = 0.f;
#pragma unroll 8
    for (int d4 = 0; d4 < 32; ++d4) {
      float4 a = Wi[d4];
      const float* wo = W_out + d4 * 48 + l;
      s += a.x * wo[0] + a.y * wo[12] + a.z * wo[24] + a.w * wo[36];
    }
    prep[t] = s;
  } else if (t < 168) {
    int l = (t - 144) % 12;
    float cs = 0.f, cb = 0.f;
#pragma unroll 8
    for (int d = 0; d < DM; ++d) {
      float w = W_out[d * 12 + l];
      cs += w;
      cb += b_in[d] * w;
    }
    if (t < 156) {
      prep[144 + l] = cb;
      prep[156 + l] = tt[0] * cs;
    } else {
      prep[168 + l] = ft[0] * cs;
    }
  }
}

// ---------------------------------------------------------------------------
// fused: one block per (b, 8-var chunk). Stage transposed x tile in LDS,
// score+rank per wave (lane=p), decode, store. All staging indices are
// compile-time-shaped: NO runtime-trip-count register arrays (scratch!).
// ---------------------------------------------------------------------------
__global__ __launch_bounds__(256) void fused_kernel(
    const float* __restrict__ x, const float* __restrict__ b_out,
    const float* __restrict__ prep, float* __restrict__ out) {
  __shared__ float xs[VB * RSTRIDE];          // 26.1 KB transposed tile
  __shared__ __align__(16) float spp[192];    // M(144) c(12) St(12) Sf(12) b_out(12)
  __shared__ unsigned long long smT[VB], smF[VB];

  const int t = threadIdx.x;
  const int chunk = blockIdx.x;  // 0..40
  const int b = blockIdx.y;      // 0..31
  const int v0 = chunk * VB;
  const bool full = (chunk < 40);
  const int nv = full ? VB : 1;

  const float* xb = x + ((size_t)(b * 64) * NV + v0) * PL;

  // ---- staging loads: compile-time register tuples, coalesced float4 ----
  float4 r0[2], r1[2], r2[2];
  int ofs[2] = {0, 0};
  if (full) {
#pragma unroll
    for (int h = 0; h < 2; ++h) {
      const int j = t + h * 256;        // pair id 0..511
      const int p = j >> 3, vv = j & 7; // lanes sweep vv fastest -> contiguous
      const float4* src = (const float4*)(xb + ((size_t)p * NV + vv) * PL);
      r0[h] = src[0];
      r1[h] = src[1];
      r2[h] = src[2];
      ofs[h] = vv * RSTRIDE + p * 13;
    }
  } else if (t < 64) {
    const float4* src = (const float4*)(xb + (size_t)t * NV * PL);
    r0[0] = src[0];
    r1[0] = src[1];
    r2[0] = src[2];
    ofs[0] = t * 13;
  }

  // ---- prep constants: 192 L2-hot floats ----
  if (t < 180) spp[t] = prep[t];
  else if (t < 192) spp[t] = b_out[t - 180];

  // ---- scatter staged registers into transposed LDS layout ----
  if (full) {
#pragma unroll
    for (int h = 0; h < 2; ++h) {
      float* d = xs + ofs[h];
      d[0] = r0[h].x; d[1] = r0[h].y; d[2] = r0[h].z; d[3] = r0[h].w;
      d[4] = r1[h].x; d[5] = r1[h].y; d[6] = r1[h].z; d[7] = r1[h].w;
      d[8] = r2[h].x; d[9] = r2[h].y; d[10] = r2[h].z; d[11] = r2[h].w;
    }
  } else if (t < 64) {
    float* d = xs + ofs[0];
    d[0] = r0[0].x; d[1] = r0[0].y; d[2] = r0[0].z; d[3] = r0[0].w;
    d[4] = r1[0].x; d[5] = r1[0].y; d[6] = r1[0].z; d[7] = r1[0].w;
    d[8] = r2[0].x; d[9] = r2[0].y; d[10] = r2[0].z; d[11] = r2[0].w;
  }
  __syncthreads();

  // ---- phase 1: scores + fused dual radix top-k; one wave per vv, lane=p ----
  const int wv = t >> 6, lane = t & 63;
  const float H = 0.86602540378443864676f;  // sqrt(3)/2
#pragma unroll
  for (int k = 0; k < 2; ++k) {
    const int vv = wv * 2 + k;
    if (vv < nv) {  // wave-uniform
      const float* xp = xs + vv * RSTRIDE + lane * 13;
      float xv[12];
#pragma unroll
      for (int i = 0; i < 12; ++i) xv[i] = xp[i];

      // coefficient of variation: std(ddof=1)/(mean+1e-6)
      float s = 0.f;
#pragma unroll
      for (int i = 0; i < 12; ++i) s += xv[i];
      const float m = s * (1.0f / 12.0f);
      float ss = 0.f;
#pragma unroll
      for (int i = 0; i < 12; ++i) {
        float d = xv[i] - m;
        ss += d * d;
      }
      const float cv = sqrtf(ss * (1.0f / 11.0f)) / (m + 1e-6f);

      // mean |rfft12| over 7 bins, even/odd folded exact 30-degree DFT
      const float e1 = xv[1] + xv[11], e2 = xv[2] + xv[10], e3 = xv[3] + xv[9],
                  e4 = xv[4] + xv[8], e5 = xv[5] + xv[7];
      const float o1 = xv[1] - xv[11], o2 = xv[2] - xv[10], o3 = xv[3] - xv[9],
                  o4 = xv[4] - xv[8], o5 = xv[5] - xv[7];
      float mag = fabsf(xv[0] + xv[6] + e1 + e2 + e3 + e4 + e5);  // k=0
      float re = xv[0] - xv[6] + H * (e1 - e5) + 0.5f * (e2 - e4);
      float im = 0.5f * (o1 + o5) + H * (o2 + o4) + o3;
      mag += sqrtf(re * re + im * im);  // k=1
      re = xv[0] + xv[6] + 0.5f * (e1 + e5) - 0.5f * (e2 + e4) - e3;
      im = H * (o1 + o2 - o4 - o5);
      mag += sqrtf(re * re + im * im);  // k=2
      re = xv[0] - xv[6] - e2 + e4;
      im = o1 - o3 + o5;
      mag += sqrtf(re * re + im * im);  // k=3
      re = xv[0] + xv[6] - 0.5f * (e1 + e2 + e4 + e5) + e3;
      im = H * (o1 - o2 + o4 - o5);
      mag += sqrtf(re * re + im * im);  // k=4
      re = xv[0] - xv[6] + H * (e5 - e1) + 0.5f * (e2 - e4);
      im = 0.5f * (o1 + o5) - H * (o2 + o4) + o3;
      mag += sqrtf(re * re + im * im);  // k=5
      re = xv[0] + xv[6] - e1 + e2 - e3 + e4 - e5;
      mag += fabsf(re);  // k=6
      const float fs = mag * (1.0f / 7.0f);

      // fused dual radix top-k: two independent ballot chains interleaved.
      // ut: rank for KT LARGEST cv; uf: rank for KF SMALLEST fs (order flip).
      const unsigned ut = ord(cv);
      const unsigned uf = ~ord(fs);
      unsigned tht = 0, thf = 0;
#pragma unroll
      for (int bit = 31; bit >= 0; --bit) {
        const unsigned ct = tht | (1u << bit);
        const unsigned cf = thf | (1u << bit);
        const unsigned long long bt = __ballot(ut >= ct);
        const unsigned long long bf = __ballot(uf >= cf);
        if (__popcll(bt) >= KT) tht = ct;
        if (__popcll(bf) >= KF) thf = cf;
      }
      const unsigned long long pre = (1ull << lane) - 1ull;
      const int gt_t = __popcll(__ballot(ut > tht));
      const int rt = __popcll(__ballot(ut == tht) & pre);
      const bool masked_t = (ut > tht) || ((ut == tht) && (rt < KT - gt_t));
      const int gt_f = __popcll(__ballot(uf > thf));
      const int rf = __popcll(__ballot(uf == thf) & pre);
      const bool masked_f = (uf > thf) || ((uf == thf) && (rf < KF - gt_f));
      const unsigned long long bkt = __ballot(!masked_t);
      const unsigned long long bkf = __ballot(!masked_f);
      if (lane == 0) {
        smT[vv] = bkt;
        smF[vv] = bkf;
      }
    }
  }
  __syncthreads();

  // ---- phase 2: decode. thread -> (p2, vv0), (p2, vv0+1); M via b128 bcast --
  const float* sM = spp;
  const float* sc = spp + 144;
  const float* sSt = spp + 156;
  const float* sSf = spp + 168;
  const float* sb = spp + 180;
  const int p2 = t >> 2;
  const int vv0 = (t & 3) * 2;
  const bool val0 = vv0 < nv, val1 = (vv0 + 1) < nv;
  float xv2[2][12], E[2][12];
#pragma unroll
  for (int j = 0; j < 2; ++j) {
    const float* xp = xs + (vv0 + j) * RSTRIDE + p2 * 13;
#pragma unroll
    for (int i = 0; i < 12; ++i) xv2[j][i] = xp[i];  // in-bounds even if !valid
  }
#pragma unroll
  for (int l = 0; l < 12; ++l) {
    E[0][l] = sc[l];
    E[1][l] = sc[l];
  }
  const float4* M4 = (const float4*)sM;
#pragma unroll
  for (int i = 0; i < 12; ++i) {  // uniform-address b128 broadcasts, no conflicts
    float4 m0 = M4[i * 3], m1 = M4[i * 3 + 1], m2 = M4[i * 3 + 2];
    float a0 = xv2[0][i], a1 = xv2[1][i];
    E[0][0] += a0 * m0.x;  E[0][1] += a0 * m0.y;
    E[0][2] += a0 * m0.z;  E[0][3] += a0 * m0.w;
    E[0][4] += a0 * m1.x;  E[0][5] += a0 * m1.y;
    E[0][6] += a0 * m1.z;  E[0][7] += a0 * m1.w;
    E[0][8] += a0 * m2.x;  E[0][9] += a0 * m2.y;
    E[0][10] += a0 * m2.z; E[0][11] += a0 * m2.w;
    E[1][0] += a1 * m0.x;  E[1][1] += a1 * m0.y;
    E[1][2] += a1 * m0.z;  E[1][3] += a1 * m0.w;
    E[1][4] += a1 * m1.x;  E[1][5] += a1 * m1.y;
    E[1][6] += a1 * m1.z;  E[1][7] += a1 * m1.w;
    E[1][8] += a1 * m2.x;  E[1][9] += a1 * m2.y;
    E[1][10] += a1 * m2.z; E[1][11] += a1 * m2.w;
  }
#pragma unroll
  for (int j = 0; j < 2; ++j) {
    if (j == 0 ? val0 : val1) {
      const int vv = vv0 + j;
      const bool kt = (smT[vv] >> p2) & 1ull;
      const bool kf = (smF[vv] >> p2) & 1ull;
      float o[12];
#pragma unroll
      for (int l = 0; l < 12; ++l) {
        float e = E[j][l];
        float at = kt ? e : sSt[l];
        float af = kf ? e : sSf[l];
        o[l] = 0.5f * (at + af) + sb[l];
      }
      float* op = out + ((size_t)(b * 64 + p2) * NV + v0 + vv) * PL;
      ((float4*)op)[0] = make_float4(o[0], o[1], o[2], o[3]);
      ((float4*)op)[1] = make_float4(o[4], o[5], o[6], o[7]);
      ((float4*)op)[2] = make_float4(o[8], o[9], o[10], o[11]);
    }
  }
}

extern "C" void kernel_launch(void* const* d_in, const int* in_sizes, int n_in,
                              void* d_out, int out_size, void* d_ws,
                              size_t ws_size, hipStream_t stream) {
  const float* x = (const float*)d_in[0];
  const float* W_in = (const float*)d_in[1];
  const float* b_in = (const float*)d_in[2];
  const float* W_out = (const float*)d_in[3];
  const float* b_out = (const float*)d_in[4];
  const float* tt = (const float*)d_in[5];
  const float* ft = (const float*)d_in[6];
  float* out = (float*)d_out;
  float* prep = (float*)d_ws;  // 180 floats

  hipLaunchKernelGGL(prep_kernel, dim3(1), dim3(192), 0, stream, W_in, b_in,
                     W_out, tt, ft, prep);
  hipLaunchKernelGGL(fused_kernel, dim3(NCHUNK, BS), dim3(256), 0, stream, x,
                     b_out, prep, out);
}

// Round 5
// 117.238 us; speedup vs baseline: 1.2584x; 1.0235x over previous
//
#include <hip/hip_runtime.h>
#include <math.h>

constexpr int BS = 32, NV = 321, PL = 12, DM = 128;
constexpr int KT = 32;  // int(64*0.5) patches masked by time criterion
constexpr int KF = 25;  // int(64*0.4) patches masked by freq criterion
constexpr int VB = 8;       // variables per block
constexpr int NCHUNK = 41;  // 40 full chunks + 1 tail chunk (nv=1)
constexpr int SST = 72;     // score row stride: (72*vv+p)%32 -> <=2-way (free)

// map float -> uint such that uint order == float order (total, -0 < +0)
__device__ __forceinline__ unsigned ord(float f) {
  unsigned u = __float_as_uint(f);
  return ((int)u < 0) ? ~u : (u | 0x80000000u);
}

// ---------------------------------------------------------------------------
// prep: M = W_in @ W_out (12x12), c = b_in @ W_out (12),
//       S_t = tt*colsum(W_out), S_f = ft*colsum(W_out), copy of b_out.
// prep floats: [0,144) M [i][l], [144,156) c, [156,168) S_t, [168,180) S_f,
//              [180,192) b_out
// ---------------------------------------------------------------------------
__global__ void prep_kernel(const float* __restrict__ W_in,
                            const float* __restrict__ b_in,
                            const float* __restrict__ W_out,
                            const float* __restrict__ b_out,
                            const float* __restrict__ tt,
                            const float* __restrict__ ft,
                            float* __restrict__ prep) {
  int t = threadIdx.x;
  if (t < 144) {
    int i = t / 12, l = t % 12;
    const float4* Wi = (const float4*)(W_in + i * DM);
    float s = 0.f;
#pragma unroll 8
    for (int d4 = 0; d4 < 32; ++d4) {
      float4 a = Wi[d4];
      const float* wo = W_out + d4 * 48 + l;
      s += a.x * wo[0] + a.y * wo[12] + a.z * wo[24] + a.w * wo[36];
    }
    prep[t] = s;
  } else if (t < 168) {
    int l = (t - 144) % 12;
    float cs = 0.f, cb = 0.f;
#pragma unroll 8
    for (int d = 0; d < DM; ++d) {
      float w = W_out[d * 12 + l];
      cs += w;
      cb += b_in[d] * w;
    }
    if (t < 156) {
      prep[144 + l] = cb;
      prep[156 + l] = tt[0] * cs;
    } else {
      prep[168 + l] = ft[0] * cs;
    }
  } else if (t < 180) {
    prep[180 + (t - 168)] = b_out[t - 168];
  }
}

// ---------------------------------------------------------------------------
// fused: one block per (b, 8-var chunk). x stays in REGISTERS end-to-end;
// only per-patch scores (2 floats) go through LDS for the cross-wave ranking.
// Thread t owns patches j = t and t+256, with p = j>>3, vv = j&7
// (consecutive lanes sweep vv -> 384B contiguous runs for loads AND stores).
// ---------------------------------------------------------------------------
__global__ __launch_bounds__(256) void fused_kernel(
    const float* __restrict__ x, const float* __restrict__ prep,
    float* __restrict__ out) {
  __shared__ float scv[VB * SST];
  __shared__ float sfs[VB * SST];
  __shared__ __align__(16) float spp[192];  // M(144) c(12) St(12) Sf(12) b(12)
  __shared__ unsigned long long smT[VB], smF[VB];

  const int t = threadIdx.x;
  const int chunk = blockIdx.x;  // 0..40
  const int b = blockIdx.y;      // 0..31
  const int v0 = chunk * VB;
  const bool full = (chunk < 40);
  const int nv = full ? VB : 1;

  const float* xb = x + ((size_t)(b * 64) * NV + v0) * PL;

  // ---- load owned patches into registers (coalesced float4) ----
  float xr[2][12];
  int pp[2], vvv[2];
  if (full) {
#pragma unroll
    for (int h = 0; h < 2; ++h) {
      const int j = t + 256 * h;
      const int p = j >> 3, vv = j & 7;
      pp[h] = p;
      vvv[h] = vv;
      const float4* src = (const float4*)(xb + ((size_t)p * NV + vv) * PL);
      float4 a = src[0], bb = src[1], c = src[2];
      xr[h][0] = a.x;  xr[h][1] = a.y;  xr[h][2] = a.z;  xr[h][3] = a.w;
      xr[h][4] = bb.x; xr[h][5] = bb.y; xr[h][6] = bb.z; xr[h][7] = bb.w;
      xr[h][8] = c.x;  xr[h][9] = c.y;  xr[h][10] = c.z; xr[h][11] = c.w;
    }
  } else {
    pp[0] = t & 63;
    vvv[0] = 0;
    pp[1] = 0;
    vvv[1] = 0;
    if (t < 64) {
      const float4* src = (const float4*)(xb + (size_t)t * NV * PL);
      float4 a = src[0], bb = src[1], c = src[2];
      xr[0][0] = a.x;  xr[0][1] = a.y;  xr[0][2] = a.z;  xr[0][3] = a.w;
      xr[0][4] = bb.x; xr[0][5] = bb.y; xr[0][6] = bb.z; xr[0][7] = bb.w;
      xr[0][8] = c.x;  xr[0][9] = c.y;  xr[0][10] = c.z; xr[0][11] = c.w;
    }
  }

  // ---- decode constants (L2-hot, 768 B) ----
  if (t < 192) spp[t] = prep[t];

  // ---- per-patch scores from registers; 2 floats/patch to LDS ----
  const float H = 0.86602540378443864676f;  // sqrt(3)/2
#pragma unroll
  for (int h = 0; h < 2; ++h) {
    const bool valid = full || (h == 0 && t < 64);
    if (valid) {
      const float* xv = xr[h];
      // coefficient of variation: std(ddof=1)/(mean+1e-6)
      float s = 0.f;
#pragma unroll
      for (int i = 0; i < 12; ++i) s += xv[i];
      const float m = s * (1.0f / 12.0f);
      float ss = 0.f;
#pragma unroll
      for (int i = 0; i < 12; ++i) {
        float d = xv[i] - m;
        ss += d * d;
      }
      const float cv = sqrtf(ss * (1.0f / 11.0f)) / (m + 1e-6f);

      // mean |rfft12| over 7 bins, even/odd folded exact 30-degree DFT
      const float e1 = xv[1] + xv[11], e2 = xv[2] + xv[10], e3 = xv[3] + xv[9],
                  e4 = xv[4] + xv[8], e5 = xv[5] + xv[7];
      const float o1 = xv[1] - xv[11], o2 = xv[2] - xv[10], o3 = xv[3] - xv[9],
                  o4 = xv[4] - xv[8], o5 = xv[5] - xv[7];
      float mag = fabsf(xv[0] + xv[6] + e1 + e2 + e3 + e4 + e5);  // k=0
      float re = xv[0] - xv[6] + H * (e1 - e5) + 0.5f * (e2 - e4);
      float im = 0.5f * (o1 + o5) + H * (o2 + o4) + o3;
      mag += sqrtf(re * re + im * im);  // k=1
      re = xv[0] + xv[6] + 0.5f * (e1 + e5) - 0.5f * (e2 + e4) - e3;
      im = H * (o1 + o2 - o4 - o5);
      mag += sqrtf(re * re + im * im);  // k=2
      re = xv[0] - xv[6] - e2 + e4;
      im = o1 - o3 + o5;
      mag += sqrtf(re * re + im * im);  // k=3
      re = xv[0] + xv[6] - 0.5f * (e1 + e2 + e4 + e5) + e3;
      im = H * (o1 - o2 + o4 - o5);
      mag += sqrtf(re * re + im * im);  // k=4
      re = xv[0] - xv[6] + H * (e5 - e1) + 0.5f * (e2 - e4);
      im = 0.5f * (o1 + o5) - H * (o2 + o4) + o3;
      mag += sqrtf(re * re + im * im);  // k=5
      re = xv[0] + xv[6] - e1 + e2 - e3 + e4 - e5;
      mag += fabsf(re);  // k=6
      const float fs = mag * (1.0f / 7.0f);

      scv[vvv[h] * SST + pp[h]] = cv;
      sfs[vvv[h] * SST + pp[h]] = fs;
    }
  }
  __syncthreads();

  // ---- dual radix top-k per (b,v): one wave per vv, lane = p ----
  const int wv = t >> 6, lane = t & 63;
#pragma unroll
  for (int k = 0; k < 2; ++k) {
    const int vv = wv * 2 + k;
    if (vv < nv) {  // wave-uniform
      const unsigned ut = ord(scv[vv * SST + lane]);   // rank KT LARGEST cv
      const unsigned uf = ~ord(sfs[vv * SST + lane]);  // rank KF SMALLEST fs
      unsigned tht = 0, thf = 0;
#pragma unroll
      for (int bit = 31; bit >= 0; --bit) {
        const unsigned ct = tht | (1u << bit);
        const unsigned cf = thf | (1u << bit);
        const unsigned long long bt = __ballot(ut >= ct);
        const unsigned long long bf = __ballot(uf >= cf);
        if (__popcll(bt) >= KT) tht = ct;
        if (__popcll(bf) >= KF) thf = cf;
      }
      const unsigned long long pre = (1ull << lane) - 1ull;
      const int gt_t = __popcll(__ballot(ut > tht));
      const int rt = __popcll(__ballot(ut == tht) & pre);
      const bool masked_t = (ut > tht) || ((ut == tht) && (rt < KT - gt_t));
      const int gt_f = __popcll(__ballot(uf > thf));
      const int rf = __popcll(__ballot(uf == thf) & pre);
      const bool masked_f = (uf > thf) || ((uf == thf) && (rf < KF - gt_f));
      const unsigned long long bkt = __ballot(!masked_t);
      const unsigned long long bkf = __ballot(!masked_f);
      if (lane == 0) {
        smT[vv] = bkt;
        smF[vv] = bkf;
      }
    }
  }
  __syncthreads();

  // ---- decode from registers; M rows via uniform b128 broadcasts ----
  float E0[12], E1[12];
#pragma unroll
  for (int l = 0; l < 12; ++l) {
    E0[l] = spp[144 + l];
    E1[l] = spp[144 + l];
  }
  const float4* M4 = (const float4*)spp;
#pragma unroll
  for (int i = 0; i < 12; ++i) {
    float4 m0 = M4[i * 3], m1 = M4[i * 3 + 1], m2 = M4[i * 3 + 2];
    float a0 = xr[0][i], a1 = xr[1][i];
    E0[0] += a0 * m0.x;  E0[1] += a0 * m0.y;
    E0[2] += a0 * m0.z;  E0[3] += a0 * m0.w;
    E0[4] += a0 * m1.x;  E0[5] += a0 * m1.y;
    E0[6] += a0 * m1.z;  E0[7] += a0 * m1.w;
    E0[8] += a0 * m2.x;  E0[9] += a0 * m2.y;
    E0[10] += a0 * m2.z; E0[11] += a0 * m2.w;
    E1[0] += a1 * m0.x;  E1[1] += a1 * m0.y;
    E1[2] += a1 * m0.z;  E1[3] += a1 * m0.w;
    E1[4] += a1 * m1.x;  E1[5] += a1 * m1.y;
    E1[6] += a1 * m1.z;  E1[7] += a1 * m1.w;
    E1[8] += a1 * m2.x;  E1[9] += a1 * m2.y;
    E1[10] += a1 * m2.z; E1[11] += a1 * m2.w;
  }
#pragma unroll
  for (int h = 0; h < 2; ++h) {
    const bool valid = full || (h == 0 && t < 64);
    if (valid) {
      const int p = pp[h], vv = vvv[h];
      const bool kt = (smT[vv] >> p) & 1ull;
      const bool kf = (smF[vv] >> p) & 1ull;
      const float* E = (h == 0) ? E0 : E1;
      float o[12];
#pragma unroll
      for (int l = 0; l < 12; ++l) {
        float e = E[l];
        float at = kt ? e : spp[156 + l];
        float af = kf ? e : spp[168 + l];
        o[l] = 0.5f * (at + af) + spp[180 + l];
      }
      float* op = out + ((size_t)(b * 64 + p) * NV + v0 + vv) * PL;
      ((float4*)op)[0] = make_float4(o[0], o[1], o[2], o[3]);
      ((float4*)op)[1] = make_float4(o[4], o[5], o[6], o[7]);
      ((float4*)op)[2] = make_float4(o[8], o[9], o[10], o[11]);
    }
  }
}

extern "C" void kernel_launch(void* const* d_in, const int* in_sizes, int n_in,
                              void* d_out, int out_size, void* d_ws,
                              size_t ws_size, hipStream_t stream) {
  const float* x = (const float*)d_in[0];
  const float* W_in = (const float*)d_in[1];
  const float* b_in = (const float*)d_in[2];
  const float* W_out = (const float*)d_in[3];
  const float* b_out = (const float*)d_in[4];
  const float* tt = (const float*)d_in[5];
  const float* ft = (const float*)d_in[6];
  float* out = (float*)d_out;
  float* prep = (float*)d_ws;  // 192 floats

  hipLaunchKernelGGL(prep_kernel, dim3(1), dim3(192), 0, stream, W_in, b_in,
                     W_out, b_out, tt, ft, prep);
  hipLaunchKernelGGL(fused_kernel, dim3(NCHUNK, BS), dim3(256), 0, stream, x,
                     prep, out);
}